// Round 1
// baseline (307.166 us; speedup 1.0000x reference)
//
#include <hip/hip_runtime.h>
#include <hip/hip_bf16.h>

// ---------------------------------------------------------------------------
// Devault_Single_CCNN: only the LAST timestep feeds the head, so we compute
// just the causal receptive field. In index space every layer is a stride-2
// kernel-5 conv: Out[q] = sum_k W[k] * In[2q+k], lengths 509->253->...->1.
// All convs run as bf16 MFMA (16x16x32), fp32 accumulate. Head is fp32.
// ---------------------------------------------------------------------------

typedef __attribute__((ext_vector_type(8))) short bfrag8;   // 8 bf16 (4 VGPR)
typedef __attribute__((ext_vector_type(4))) float floatx4;  // MFMA acc

__device__ __forceinline__ unsigned short f2bf(float f) {
  union { float f; unsigned u; } v; v.f = f;
  unsigned r = v.u + 0x7fffu + ((v.u >> 16) & 1u);  // RNE
  return (unsigned short)(r >> 16);
}
__device__ __forceinline__ float bf2f(unsigned short h) {
  union { unsigned u; float f; } v; v.u = ((unsigned)h) << 16;
  return v.f;
}

// ---------------------------------------------------------------------------
// Weight norm + pre-swizzle into MFMA B-fragment order.
// W[o][kk], kk = tap*CPAD + c.  B-frag: lane=(o&15)|(kg<<4), elem i: kk =
// ks*32 + kg*8 + i.  Stored as WB[((ot*NKS+ks)*64+lane)*8 + i], bf16.
// ---------------------------------------------------------------------------
__global__ void k_wnorm(const float* __restrict__ v0, const float* __restrict__ g0,
                        const float* __restrict__ vr, const float* __restrict__ gr,
                        unsigned short* __restrict__ WB0, unsigned short* __restrict__ WBr) {
  __shared__ float red[8];
  const int tid = threadIdx.x;
  if (blockIdx.x < 128) {               // layer 0: o = blockIdx.x, K=1500 -> pad 1600
    const int o = blockIdx.x;
    const float* v = v0 + o * 1500;
    float ss = 0.f;
    for (int i = tid; i < 1500; i += 256) { float x = v[i]; ss += x * x; }
    for (int off = 32; off; off >>= 1) ss += __shfl_down(ss, off, 64);
    if ((tid & 63) == 0) red[tid >> 6] = ss;
    __syncthreads();
    const float scale = g0[o] * rsqrtf(red[0] + red[1] + red[2] + red[3]);
    const int ot = o >> 4;
    for (int kk = tid; kk < 1600; kk += 256) {
      const int tap = kk / 320, c = kk % 320;
      const float w = (c < 300) ? v[c * 5 + tap] * scale : 0.f;
      const int ks = kk >> 5;
      const int lane = (o & 15) | (((kk >> 3) & 3) << 4);
      WB0[(((ot * 50 + ks) * 64 + lane) << 3) | (kk & 7)] = f2bf(w);
    }
  } else {                              // layers 1..6: K = 640
    const int idx = blockIdx.x - 128;
    const int l = idx >> 7, o = idx & 127;
    const float* v = vr + (size_t)(l * 128 + o) * 640;
    float ss = 0.f;
    for (int i = tid; i < 640; i += 256) { float x = v[i]; ss += x * x; }
    for (int off = 32; off; off >>= 1) ss += __shfl_down(ss, off, 64);
    if ((tid & 63) == 0) red[tid >> 6] = ss;
    __syncthreads();
    const float scale = gr[l * 128 + o] * rsqrtf(red[0] + red[1] + red[2] + red[3]);
    unsigned short* WB = WBr + (size_t)l * 81920;
    const int ot = o >> 4;
    for (int kk = tid; kk < 640; kk += 256) {
      const int tap = kk >> 7, c = kk & 127;
      const float w = v[c * 5 + tap] * scale;
      const int ks = kk >> 5;
      const int lane = (o & 15) | (((kk >> 3) & 3) << 4);
      WB[(((ot * 20 + ks) * 64 + lane) << 3) | (kk & 7)] = f2bf(w);
    }
  }
}

// ---------------------------------------------------------------------------
// Gather embeddings for the 509 needed timesteps -> In0[b][p][c] bf16,
// rows padded to 516, channels padded 300->320 (zeros).
// ---------------------------------------------------------------------------
__global__ void k_gather(const int* __restrict__ tokens, const float* __restrict__ emb,
                         unsigned short* __restrict__ In0) {
  const int p = blockIdx.x, b = blockIdx.y, t = threadIdx.x;  // 320 threads
  const int tok = tokens[b * 2048 + 1539 + p];                // time = T-509+p
  unsigned short* dst = In0 + ((size_t)b * 516 + p) * 320;
  const float v = (t < 300) ? emb[(size_t)tok * 300 + t] : 0.f;
  dst[t] = f2bf(v);
}

// ---------------------------------------------------------------------------
// Universal stride-2 kernel-5 conv as MFMA GEMM. One wave per (b, 16-q tile).
// A-frag: lane -> q = qt*16+(lane&15), kk = ks*32+(lane>>4)*8 (+i contiguous)
//   = one dwordx4 from In[b][2q+tap][c..c+7].
// B-frag: pre-swizzled WB, fully coalesced dwordx4.
// D: q = qt*16+(lane>>4)*4+r, o = ot*16+(lane&15). bias+relu, store bf16.
// ---------------------------------------------------------------------------
template<int CPAD, int NKS, int INROWS, int OUTROWS>
__global__ __launch_bounds__(64)
void k_conv(const unsigned short* __restrict__ In, unsigned short* __restrict__ Out,
            const unsigned short* __restrict__ WB, const float* __restrict__ bias,
            int Nout) {
  const int lane = threadIdx.x;
  const int b = blockIdx.y;
  const int qt = blockIdx.x;
  const int q = (qt << 4) + (lane & 15);
  const int kg = lane >> 4;
  floatx4 acc[8];
#pragma unroll
  for (int i = 0; i < 8; ++i) acc[i] = floatx4{0.f, 0.f, 0.f, 0.f};
  const unsigned short* in_b = In + (size_t)b * INROWS * CPAD;
  for (int ks = 0; ks < NKS; ++ks) {
    const int kk = (ks << 5) + (kg << 3);
    const int tap = kk / CPAD;          // compile-time divisor
    const int c = kk % CPAD;
    bfrag8 a = *(const bfrag8*)(in_b + (2 * q + tap) * CPAD + c);
    const unsigned short* wb = WB + (ks << 9) + (lane << 3);
#pragma unroll
    for (int ot = 0; ot < 8; ++ot) {
      bfrag8 bf = *(const bfrag8*)(wb + ((ot * NKS) << 9));
      acc[ot] = __builtin_amdgcn_mfma_f32_16x16x32_bf16(a, bf, acc[ot], 0, 0, 0);
    }
  }
  const int q0 = (qt << 4) + (kg << 2);
#pragma unroll
  for (int ot = 0; ot < 8; ++ot) {
    const int o = (ot << 4) + (lane & 15);
    const float bv = bias[o];
#pragma unroll
    for (int r = 0; r < 4; ++r) {
      const int qq = q0 + r;
      if (qq < Nout) {
        float v = acc[ot][r] + bv;
        v = v > 0.f ? v : 0.f;
        Out[((size_t)b * OUTROWS + qq) * 128 + o] = f2bf(v);
      }
    }
  }
}

// ---------------------------------------------------------------------------
// FC head: combo = [A6 (128, bf16), de_feature (11)] -> 64 -> 32 -> 1 (fp32)
// ---------------------------------------------------------------------------
__global__ void k_head(const unsigned short* __restrict__ A6, const float* __restrict__ de,
                       const float* __restrict__ w1, const float* __restrict__ b1,
                       const float* __restrict__ w2, const float* __restrict__ b2,
                       const float* __restrict__ w3, const float* __restrict__ b3,
                       float* __restrict__ out) {
  const int b = blockIdx.x, t = threadIdx.x;  // 64 threads
  __shared__ float combo[139];
  __shared__ float h1[64];
  __shared__ float h2[32];
  for (int j = t; j < 139; j += 64)
    combo[j] = (j < 128) ? bf2f(A6[b * 128 + j]) : de[b * 11 + (j - 128)];
  __syncthreads();
  float s = b1[t];
  for (int j = 0; j < 139; ++j) s += w1[t * 139 + j] * combo[j];
  h1[t] = fmaxf(s, 0.f);
  __syncthreads();
  if (t < 32) {
    float s2 = b2[t];
    for (int j = 0; j < 64; ++j) s2 += w2[t * 64 + j] * h1[j];
    h2[t] = fmaxf(s2, 0.f);
  }
  __syncthreads();
  if (t == 0) {
    float s3 = b3[0];
    for (int j = 0; j < 32; ++j) s3 += w3[j] * h2[j];
    out[b] = s3;
  }
}

// ---------------------------------------------------------------------------
extern "C" void kernel_launch(void* const* d_in, const int* in_sizes, int n_in,
                              void* d_out, int out_size, void* d_ws, size_t ws_size,
                              hipStream_t stream) {
  const int*   tokens = (const int*)  d_in[0];
  const float* de     = (const float*)d_in[1];
  const float* emb    = (const float*)d_in[2];
  const float* v0     = (const float*)d_in[3];
  const float* g0     = (const float*)d_in[4];
  const float* b0     = (const float*)d_in[5];
  const float* vr     = (const float*)d_in[6];
  const float* gr     = (const float*)d_in[7];
  const float* br     = (const float*)d_in[8];
  const float* w1     = (const float*)d_in[9];
  const float* b1     = (const float*)d_in[10];
  const float* w2     = (const float*)d_in[11];
  const float* b2     = (const float*)d_in[12];
  const float* w3     = (const float*)d_in[13];
  const float* b3     = (const float*)d_in[14];
  float* out = (float*)d_out;

  char* w = (char*)d_ws;
  unsigned short* WB0 = (unsigned short*)(w + 0);         // 128x1600 bf16 = 409.6 KB
  unsigned short* WBr = (unsigned short*)(w + 409600);    // 6 x 128x640 bf16
  unsigned short* In0 = (unsigned short*)(w + 1392640);   // [64][516][320] bf16
  unsigned short* A0  = (unsigned short*)(w + 22528000);  // [64][260][128]
  unsigned short* A1  = (unsigned short*)(w + 26787840);  // [64][132][128]
  unsigned short* A2  = (unsigned short*)(w + 28950528);  // [64][68][128]
  unsigned short* A3  = (unsigned short*)(w + 30064640);  // [64][36][128]
  unsigned short* A4  = (unsigned short*)(w + 30654464);  // [64][36][128]
  unsigned short* A5  = (unsigned short*)(w + 31244288);  // [64][36][128]
  unsigned short* A6  = (unsigned short*)(w + 31834112);  // [64][128]

  hipLaunchKernelGGL(k_wnorm, dim3(896), dim3(256), 0, stream, v0, g0, vr, gr, WB0, WBr);
  hipLaunchKernelGGL(k_gather, dim3(509, 64), dim3(320), 0, stream, tokens, emb, In0);
  hipLaunchKernelGGL((k_conv<320,50,516,260>), dim3(16,64), dim3(64), 0, stream, In0, A0, WB0, b0, 253);
  hipLaunchKernelGGL((k_conv<128,20,260,132>), dim3(8,64),  dim3(64), 0, stream, A0, A1, WBr + 0*81920, br + 0*128, 125);
  hipLaunchKernelGGL((k_conv<128,20,132,68>),  dim3(4,64),  dim3(64), 0, stream, A1, A2, WBr + 1*81920, br + 1*128, 61);
  hipLaunchKernelGGL((k_conv<128,20,68,36>),   dim3(2,64),  dim3(64), 0, stream, A2, A3, WBr + 2*81920, br + 2*128, 29);
  hipLaunchKernelGGL((k_conv<128,20,36,36>),   dim3(1,64),  dim3(64), 0, stream, A3, A4, WBr + 3*81920, br + 3*128, 13);
  hipLaunchKernelGGL((k_conv<128,20,36,36>),   dim3(1,64),  dim3(64), 0, stream, A4, A5, WBr + 4*81920, br + 4*128, 5);
  hipLaunchKernelGGL((k_conv<128,20,36,1>),    dim3(1,64),  dim3(64), 0, stream, A5, A6, WBr + 5*81920, br + 5*128, 1);
  hipLaunchKernelGGL(k_head, dim3(64), dim3(64), 0, stream, A6, de, w1, b1, w2, b2, w3, b3, out);
}

// Round 2
// 126.361 us; speedup vs baseline: 2.4309x; 2.4309x over previous
//
#include <hip/hip_runtime.h>

// ---------------------------------------------------------------------------
// Devault_Single_CCNN: only the LAST timestep feeds the head, so we compute
// just the causal receptive field. In index space every layer is a stride-2
// kernel-5 conv: Out[q] = sum_k W[k] * In[2q+k], lengths 509->253->...->1.
// bf16 MFMA 16x16x32, fp32 accumulate. 3 dispatches:
//   k_prep  : weight-norm+B-swizzle  ||  embedding gather (fused, disjoint blocks)
//   k_conv0 : layer 0 (K=1600), 8 waves/block each 1 ot x 2 m-tiles
//   k_rest  : layers 1-6 + FC head, one block per batch, LDS ping-pong
// ---------------------------------------------------------------------------

typedef __attribute__((ext_vector_type(8))) short bfrag8;   // 8 bf16
typedef __attribute__((ext_vector_type(4))) float floatx4;  // MFMA acc
typedef __attribute__((ext_vector_type(4))) short short4v;
typedef __attribute__((ext_vector_type(4))) float float4v;

__device__ __forceinline__ unsigned short f2bf(float f) {
  union { float f; unsigned u; } v; v.f = f;
  unsigned r = v.u + 0x7fffu + ((v.u >> 16) & 1u);  // RNE
  return (unsigned short)(r >> 16);
}
__device__ __forceinline__ float bf2f(unsigned short h) {
  union { unsigned u; float f; } v; v.u = ((unsigned)h) << 16;
  return v.f;
}

// ---------------------------------------------------------------------------
// k_prep: blocks [0,896) do weight-norm + MFMA-B pre-swizzle;
//         blocks [896,..) gather embeddings (fp32 -> bf16, pad 300->320,
//         rows 509..515 zeroed so conv0 never reads garbage).
// WB layout: WB[((ot*NKS + ks)*64 + lane)*8 + i] with lane=(o&15)|(kg<<4),
//            kk = ks*32 + kg*8 + i (tap-major: kk = tap*CPAD + c).
// ---------------------------------------------------------------------------
__global__ __launch_bounds__(256)
void k_prep(const float* __restrict__ v0, const float* __restrict__ g0,
            const float* __restrict__ vr, const float* __restrict__ gr,
            const int* __restrict__ tokens, const float* __restrict__ emb,
            unsigned short* __restrict__ WB0, unsigned short* __restrict__ WBr,
            unsigned short* __restrict__ In0) {
  const int tid = threadIdx.x;
  const int blk = blockIdx.x;
  if (blk >= 896) {                      // ---- gather part ----
    const int nthreads = (gridDim.x - 896) << 8;
    const int TOT = 64 * 516 * 80;       // b x padded-row x 4-ch quad
    for (int idx = ((blk - 896) << 8) + tid; idx < TOT; idx += nthreads) {
      const int q4 = idx % 80;
      const int rem = idx / 80;
      const int p = rem % 516;
      const int b = rem / 516;
      const int c0 = q4 << 2;
      short4v o = {0, 0, 0, 0};
      if (p < 509 && c0 < 300) {
        const int tok = tokens[b * 2048 + 1539 + p];   // time = T-509+p
        const float4v v = *(const float4v*)(emb + (size_t)tok * 300 + c0);
        o[0] = (short)f2bf(v[0]); o[1] = (short)f2bf(v[1]);
        o[2] = (short)f2bf(v[2]); o[3] = (short)f2bf(v[3]);
      }
      *(short4v*)(In0 + ((size_t)b * 516 + p) * 320 + c0) = o;
    }
    return;
  }
  // ---- weight-norm part ----
  __shared__ float red[4];
  if (blk < 128) {                       // layer 0: K=1500 -> pad 1600
    const int o = blk;
    const float* v = v0 + o * 1500;
    float ss = 0.f;
    for (int i = tid; i < 1500; i += 256) { float x = v[i]; ss += x * x; }
    for (int off = 32; off; off >>= 1) ss += __shfl_down(ss, off, 64);
    if ((tid & 63) == 0) red[tid >> 6] = ss;
    __syncthreads();
    const float scale = g0[o] * rsqrtf(red[0] + red[1] + red[2] + red[3]);
    const int ot = o >> 4;
    for (int kk = tid; kk < 1600; kk += 256) {
      const int tap = kk / 320, c = kk % 320;
      const float w = (c < 300) ? v[c * 5 + tap] * scale : 0.f;
      const int ks = kk >> 5;
      const int lane = (o & 15) | (((kk >> 3) & 3) << 4);
      WB0[(((ot * 50 + ks) * 64 + lane) << 3) | (kk & 7)] = f2bf(w);
    }
  } else {                               // layers 1..6: K=640
    const int idx = blk - 128;
    const int l = idx >> 7, o = idx & 127;
    const float* v = vr + (size_t)(l * 128 + o) * 640;
    float ss = 0.f;
    for (int i = tid; i < 640; i += 256) { float x = v[i]; ss += x * x; }
    for (int off = 32; off; off >>= 1) ss += __shfl_down(ss, off, 64);
    if ((tid & 63) == 0) red[tid >> 6] = ss;
    __syncthreads();
    const float scale = gr[l * 128 + o] * rsqrtf(red[0] + red[1] + red[2] + red[3]);
    unsigned short* WB = WBr + (size_t)l * 81920;
    const int ot = o >> 4;
    for (int kk = tid; kk < 640; kk += 256) {
      const int tap = kk >> 7, c = kk & 127;
      const float w = v[c * 5 + tap] * scale;
      const int ks = kk >> 5;
      const int lane = (o & 15) | (((kk >> 3) & 3) << 4);
      WB[(((ot * 20 + ks) * 64 + lane) << 3) | (kk & 7)] = f2bf(w);
    }
  }
}

// ---------------------------------------------------------------------------
// k_conv0: layer 0. grid (8 qt-tiles of 32 rows, 64 b) x 512 threads.
// Wave w handles ot=w, m-subtiles {qt*32, qt*32+16}. Full unroll, tap-major.
// ---------------------------------------------------------------------------
__global__ __launch_bounds__(512)
void k_conv0(const unsigned short* __restrict__ In, unsigned short* __restrict__ Out,
             const unsigned short* __restrict__ WB, const float* __restrict__ bias) {
  const int tid = threadIdx.x;
  const int lane = tid & 63;
  const int ot = tid >> 6;             // 0..7
  const int qt = blockIdx.x;           // 0..7
  const int b = blockIdx.y;
  const int kg = lane >> 4, qb = lane & 15;
  const unsigned short* in_b = In + (size_t)b * 516 * 320;
  const unsigned short* wb = WB + (((size_t)ot * 50) << 9) + (lane << 3);
  floatx4 acc0 = {0.f, 0.f, 0.f, 0.f}, acc1 = {0.f, 0.f, 0.f, 0.f};
  const int r0 = 2 * ((qt << 5) + qb); // input row of m-tile0 (tap 0)
#pragma unroll
  for (int tap = 0; tap < 5; ++tap) {
#pragma unroll
    for (int cs = 0; cs < 10; ++cs) {
      const int c = (cs << 5) + (kg << 3);
      const int ks = tap * 10 + cs;
      const bfrag8 bf = *(const bfrag8*)(wb + (ks << 9));
      const bfrag8 a0 = *(const bfrag8*)(in_b + (r0 + tap) * 320 + c);
      const bfrag8 a1 = *(const bfrag8*)(in_b + (r0 + 32 + tap) * 320 + c);
      acc0 = __builtin_amdgcn_mfma_f32_16x16x32_bf16(a0, bf, acc0, 0, 0, 0);
      acc1 = __builtin_amdgcn_mfma_f32_16x16x32_bf16(a1, bf, acc1, 0, 0, 0);
    }
  }
  const int o = (ot << 4) + qb;
  const float bv = bias[o];
  unsigned short* out_b = Out + (size_t)b * 260 * 128 + o;
#pragma unroll
  for (int mt = 0; mt < 2; ++mt) {
    const floatx4 acc = mt ? acc1 : acc0;
#pragma unroll
    for (int r = 0; r < 4; ++r) {
      const int qq = (qt << 5) + (mt << 4) + (kg << 2) + r;
      if (qq < 253) out_b[qq * 128] = f2bf(fmaxf(acc[r] + bv, 0.f));
    }
  }
}

// ---------------------------------------------------------------------------
// k_rest helpers. LDS tiles are [row][128] bf16 with byte ^= (row&7)<<4
// swizzle (breaks the 256B-row-stride bank conflict on ds_read_b128).
// Garbage in rows >= Mvalid is confined to masked output lanes (MFMA output
// row m depends only on A row m), so no NaN can escape.
// ---------------------------------------------------------------------------
template<int NT>
__device__ __forceinline__ void store_out(const floatx4* acc, unsigned short* lout,
                                          const float* __restrict__ bias, int Mout,
                                          int lane, int ot) {
  const int kg = lane >> 4, qb = lane & 15;
  const int o = (ot << 4) + qb;
  const float bv = bias[o];
  char* bo = (char*)lout;
#pragma unroll
  for (int mt = 0; mt < NT; ++mt)
#pragma unroll
    for (int r = 0; r < 4; ++r) {
      const int qq = (mt << 4) + (kg << 2) + r;
      if (qq < Mout) {
        const float v = fmaxf(acc[mt][r] + bv, 0.f);
        const int byte = ((qq << 8) + (o << 1)) ^ ((qq & 7) << 4);
        *(unsigned short*)(bo + byte) = f2bf(v);
      }
    }
}

template<int NT>  // layer 1: A from global (L2-hot), mt-inner for 8-deep ILP
__device__ __forceinline__ void conv_glob(const unsigned short* __restrict__ gin,
                                          unsigned short* lout,
                                          const unsigned short* __restrict__ WB,
                                          const float* __restrict__ bias, int Mout,
                                          int lane, int ot) {
  floatx4 acc[NT];
#pragma unroll
  for (int i = 0; i < NT; ++i) acc[i] = floatx4{0.f, 0.f, 0.f, 0.f};
  const int kg = lane >> 4, qb = lane & 15;
  const unsigned short* wb = WB + ((ot * 20) << 9) + (lane << 3);
#pragma unroll
  for (int tap = 0; tap < 5; ++tap)
#pragma unroll
    for (int cs = 0; cs < 4; ++cs) {
      const int c = (cs << 5) + (kg << 3);
      const int ks = (tap << 2) + cs;
      const bfrag8 bf = *(const bfrag8*)(wb + (ks << 9));
#pragma unroll
      for (int mt = 0; mt < NT; ++mt) {
        const int row = 2 * ((mt << 4) + qb) + tap;
        const bfrag8 a = *(const bfrag8*)(gin + row * 128 + c);
        acc[mt] = __builtin_amdgcn_mfma_f32_16x16x32_bf16(a, bf, acc[mt], 0, 0, 0);
      }
    }
  store_out<NT>(acc, lout, bias, Mout, lane, ot);
}

template<int NT>  // layers 2..6: A from swizzled LDS
__device__ __forceinline__ void conv_lds(const unsigned short* lin,
                                         unsigned short* lout,
                                         const unsigned short* __restrict__ WB,
                                         const float* __restrict__ bias, int Mout,
                                         int lane, int ot) {
  floatx4 acc[NT];
#pragma unroll
  for (int i = 0; i < NT; ++i) acc[i] = floatx4{0.f, 0.f, 0.f, 0.f};
  const int kg = lane >> 4, qb = lane & 15;
  const unsigned short* wb = WB + ((ot * 20) << 9) + (lane << 3);
  const char* bi = (const char*)lin;
#pragma unroll
  for (int tap = 0; tap < 5; ++tap)
#pragma unroll
    for (int cs = 0; cs < 4; ++cs) {
      const int c = (cs << 5) + (kg << 3);
      const int ks = (tap << 2) + cs;
      const bfrag8 bf = *(const bfrag8*)(wb + (ks << 9));
#pragma unroll
      for (int mt = 0; mt < NT; ++mt) {
        const int row = 2 * ((mt << 4) + qb) + tap;
        const int byte = ((row << 8) + (c << 1)) ^ ((row & 7) << 4);
        const bfrag8 a = *(const bfrag8*)(bi + byte);
        acc[mt] = __builtin_amdgcn_mfma_f32_16x16x32_bf16(a, bf, acc[mt], 0, 0, 0);
      }
    }
  store_out<NT>(acc, lout, bias, Mout, lane, ot);
}

// ---------------------------------------------------------------------------
// k_rest: one block per batch (64 blocks x 512 threads). Layers 1-6 + head.
// Valid row counts: 253 ->125 ->61 ->29 ->13 ->5 ->1.
// ---------------------------------------------------------------------------
__global__ __launch_bounds__(512)
void k_rest(const unsigned short* __restrict__ A0, const unsigned short* __restrict__ WBr,
            const float* __restrict__ br, const float* __restrict__ de,
            const float* __restrict__ w1, const float* __restrict__ b1,
            const float* __restrict__ w2, const float* __restrict__ b2,
            const float* __restrict__ w3, const float* __restrict__ b3,
            float* __restrict__ out) {
  __shared__ unsigned short bufA[132 * 128];   // 33.8 KB
  __shared__ unsigned short bufB[68 * 128];    // 17.4 KB
  __shared__ float h1[64], h2[32];
  const int tid = threadIdx.x;
  const int lane = tid & 63, ot = tid >> 6;
  const int b = blockIdx.x;

  conv_glob<8>(A0 + (size_t)b * 260 * 128, bufA, WBr + 0 * 81920, br + 0,   125, lane, ot);
  __syncthreads();
  conv_lds<4>(bufA, bufB, WBr + 1 * 81920, br + 128, 61, lane, ot);
  __syncthreads();
  conv_lds<2>(bufB, bufA, WBr + 2 * 81920, br + 256, 29, lane, ot);
  __syncthreads();
  conv_lds<1>(bufA, bufB, WBr + 3 * 81920, br + 384, 13, lane, ot);
  __syncthreads();
  conv_lds<1>(bufB, bufA, WBr + 4 * 81920, br + 512, 5, lane, ot);
  __syncthreads();
  conv_lds<1>(bufA, bufB, WBr + 5 * 81920, br + 640, 1, lane, ot);
  __syncthreads();

  // head: combo = [bufB row 0 (128 bf16, row0 swizzle = identity), de (11)]
  const unsigned short* o6 = bufB;
  if (tid < 64) {
    float s = b1[tid];
    const float* wrow = w1 + tid * 139;
    for (int j = 0; j < 128; ++j) s += wrow[j] * bf2f(o6[j]);
    for (int j = 0; j < 11; ++j) s += wrow[128 + j] * de[b * 11 + j];
    h1[tid] = fmaxf(s, 0.f);
  }
  __syncthreads();
  if (tid < 32) {
    float s = b2[tid];
    for (int j = 0; j < 64; ++j) s += w2[tid * 64 + j] * h1[j];
    h2[tid] = fmaxf(s, 0.f);
  }
  __syncthreads();
  if (tid == 0) {
    float s = b3[0];
    for (int j = 0; j < 32; ++j) s += w3[j] * h2[j];
    out[b] = s;
  }
}

// ---------------------------------------------------------------------------
extern "C" void kernel_launch(void* const* d_in, const int* in_sizes, int n_in,
                              void* d_out, int out_size, void* d_ws, size_t ws_size,
                              hipStream_t stream) {
  const int*   tokens = (const int*)  d_in[0];
  const float* de     = (const float*)d_in[1];
  const float* emb    = (const float*)d_in[2];
  const float* v0     = (const float*)d_in[3];
  const float* g0     = (const float*)d_in[4];
  const float* b0     = (const float*)d_in[5];
  const float* vr     = (const float*)d_in[6];
  const float* gr     = (const float*)d_in[7];
  const float* br     = (const float*)d_in[8];
  const float* w1     = (const float*)d_in[9];
  const float* b1     = (const float*)d_in[10];
  const float* w2     = (const float*)d_in[11];
  const float* b2     = (const float*)d_in[12];
  const float* w3     = (const float*)d_in[13];
  const float* b3     = (const float*)d_in[14];
  float* out = (float*)d_out;

  char* w = (char*)d_ws;
  unsigned short* WB0 = (unsigned short*)(w + 0);         // 128x1600 bf16
  unsigned short* WBr = (unsigned short*)(w + 409600);    // 6 x 128x640 bf16
  unsigned short* In0 = (unsigned short*)(w + 1392640);   // [64][516][320] bf16
  unsigned short* A0  = (unsigned short*)(w + 22528000);  // [64][260][128] bf16

  hipLaunchKernelGGL(k_prep, dim3(896 + 2048), dim3(256), 0, stream,
                     v0, g0, vr, gr, tokens, emb, WB0, WBr, In0);
  hipLaunchKernelGGL(k_conv0, dim3(8, 64), dim3(512), 0, stream, In0, A0, WB0, b0);
  hipLaunchKernelGGL(k_rest, dim3(64), dim3(512), 0, stream,
                     A0, WBr, br, de, w1, b1, w2, b2, w3, b3, out);
}

// Round 3
// 111.561 us; speedup vs baseline: 2.7533x; 1.1327x over previous
//
#include <hip/hip_runtime.h>

// ---------------------------------------------------------------------------
// Devault_Single_CCNN: only the LAST timestep feeds the head, so we compute
// just the causal receptive field. In index space every layer is a stride-2
// kernel-5 conv: Out[q] = sum_k W[k] * In[2q+k], lengths 509->253->...->1.
// bf16 MFMA 16x16x32, fp32 accumulate. 3 dispatches:
//   k_prep  : weight-norm+B-swizzle  ||  embedding gather
//   k_conv0 : layer 0 (K=1600), 512 blocks x 8 waves
//   k_rest  : layers 1-6 + FC head, one block per batch, all-LDS with
//             mt-split waves (no duplicated A-reads) and ((row>>1)&7)<<4
//             swizzle (step-2 row access -> 2-way conflict = free).
// ---------------------------------------------------------------------------

typedef __attribute__((ext_vector_type(8))) short bfrag8;   // 8 bf16
typedef __attribute__((ext_vector_type(4))) float floatx4;  // MFMA acc
typedef __attribute__((ext_vector_type(4))) short short4v;
typedef __attribute__((ext_vector_type(4))) float float4v;

__device__ __forceinline__ unsigned short f2bf(float f) {
  union { float f; unsigned u; } v; v.f = f;
  unsigned r = v.u + 0x7fffu + ((v.u >> 16) & 1u);  // RNE
  return (unsigned short)(r >> 16);
}
__device__ __forceinline__ float bf2f(unsigned short h) {
  union { unsigned u; float f; } v; v.u = ((unsigned)h) << 16;
  return v.f;
}

// ---------------------------------------------------------------------------
// k_prep: blocks [0,896) weight-norm + MFMA-B pre-swizzle; rest gather emb.
// WB layout: WB[((ot*NKS + ks)*64 + lane)*8 + i], lane=(o&15)|(kg<<4),
//            kk = ks*32 + kg*8 + i (kk = tap*CPAD + c).
// ---------------------------------------------------------------------------
__global__ __launch_bounds__(256)
void k_prep(const float* __restrict__ v0, const float* __restrict__ g0,
            const float* __restrict__ vr, const float* __restrict__ gr,
            const int* __restrict__ tokens, const float* __restrict__ emb,
            unsigned short* __restrict__ WB0, unsigned short* __restrict__ WBr,
            unsigned short* __restrict__ In0) {
  const int tid = threadIdx.x;
  const int blk = blockIdx.x;
  if (blk >= 896) {                      // ---- gather part ----
    const int nthreads = (gridDim.x - 896) << 8;
    const int TOT = 64 * 516 * 80;       // b x padded-row x 4-ch quad
    for (int idx = ((blk - 896) << 8) + tid; idx < TOT; idx += nthreads) {
      const int q4 = idx % 80;
      const int rem = idx / 80;
      const int p = rem % 516;
      const int b = rem / 516;
      const int c0 = q4 << 2;
      short4v o = {0, 0, 0, 0};
      if (p < 509 && c0 < 300) {
        const int tok = tokens[b * 2048 + 1539 + p];   // time = T-509+p
        const float4v v = *(const float4v*)(emb + (size_t)tok * 300 + c0);
        o[0] = (short)f2bf(v[0]); o[1] = (short)f2bf(v[1]);
        o[2] = (short)f2bf(v[2]); o[3] = (short)f2bf(v[3]);
      }
      *(short4v*)(In0 + ((size_t)b * 516 + p) * 320 + c0) = o;
    }
    return;
  }
  // ---- weight-norm part ----
  __shared__ float red[4];
  if (blk < 128) {                       // layer 0: K=1500 -> pad 1600
    const int o = blk;
    const float* v = v0 + o * 1500;
    float ss = 0.f;
    for (int i = tid; i < 1500; i += 256) { float x = v[i]; ss += x * x; }
    for (int off = 32; off; off >>= 1) ss += __shfl_down(ss, off, 64);
    if ((tid & 63) == 0) red[tid >> 6] = ss;
    __syncthreads();
    const float scale = g0[o] * rsqrtf(red[0] + red[1] + red[2] + red[3]);
    const int ot = o >> 4;
    for (int kk = tid; kk < 1600; kk += 256) {
      const int tap = kk / 320, c = kk % 320;
      const float w = (c < 300) ? v[c * 5 + tap] * scale : 0.f;
      const int ks = kk >> 5;
      const int lane = (o & 15) | (((kk >> 3) & 3) << 4);
      WB0[(((ot * 50 + ks) * 64 + lane) << 3) | (kk & 7)] = f2bf(w);
    }
  } else {                               // layers 1..6: K=640
    const int idx = blk - 128;
    const int l = idx >> 7, o = idx & 127;
    const float* v = vr + (size_t)(l * 128 + o) * 640;
    float ss = 0.f;
    for (int i = tid; i < 640; i += 256) { float x = v[i]; ss += x * x; }
    for (int off = 32; off; off >>= 1) ss += __shfl_down(ss, off, 64);
    if ((tid & 63) == 0) red[tid >> 6] = ss;
    __syncthreads();
    const float scale = gr[l * 128 + o] * rsqrtf(red[0] + red[1] + red[2] + red[3]);
    unsigned short* WB = WBr + (size_t)l * 81920;
    const int ot = o >> 4;
    for (int kk = tid; kk < 640; kk += 256) {
      const int tap = kk >> 7, c = kk & 127;
      const float w = v[c * 5 + tap] * scale;
      const int ks = kk >> 5;
      const int lane = (o & 15) | (((kk >> 3) & 3) << 4);
      WB[(((ot * 20 + ks) * 64 + lane) << 3) | (kk & 7)] = f2bf(w);
    }
  }
}

// ---------------------------------------------------------------------------
// k_conv0: layer 0. grid (8 qt-tiles of 32 rows, 64 b) x 512 threads.
// Wave w handles ot=w, m-subtiles {qt*32, qt*32+16}. Full unroll, tap-major.
// ---------------------------------------------------------------------------
__global__ __launch_bounds__(512)
void k_conv0(const unsigned short* __restrict__ In, unsigned short* __restrict__ Out,
             const unsigned short* __restrict__ WB, const float* __restrict__ bias) {
  const int tid = threadIdx.x;
  const int lane = tid & 63;
  const int ot = tid >> 6;             // 0..7
  const int qt = blockIdx.x;           // 0..7
  const int b = blockIdx.y;
  const int kg = lane >> 4, qb = lane & 15;
  const unsigned short* in_b = In + (size_t)b * 516 * 320;
  const unsigned short* wb = WB + (((size_t)ot * 50) << 9) + (lane << 3);
  floatx4 acc0 = {0.f, 0.f, 0.f, 0.f}, acc1 = {0.f, 0.f, 0.f, 0.f};
  const int r0 = 2 * ((qt << 5) + qb); // input row of m-tile0 (tap 0)
#pragma unroll
  for (int tap = 0; tap < 5; ++tap) {
#pragma unroll
    for (int cs = 0; cs < 10; ++cs) {
      const int c = (cs << 5) + (kg << 3);
      const int ks = tap * 10 + cs;
      const bfrag8 bf = *(const bfrag8*)(wb + (ks << 9));
      const bfrag8 a0 = *(const bfrag8*)(in_b + (r0 + tap) * 320 + c);
      const bfrag8 a1 = *(const bfrag8*)(in_b + (r0 + 32 + tap) * 320 + c);
      acc0 = __builtin_amdgcn_mfma_f32_16x16x32_bf16(a0, bf, acc0, 0, 0, 0);
      acc1 = __builtin_amdgcn_mfma_f32_16x16x32_bf16(a1, bf, acc1, 0, 0, 0);
    }
  }
  const int o = (ot << 4) + qb;
  const float bv = bias[o];
  unsigned short* out_b = Out + (size_t)b * 260 * 128 + o;
#pragma unroll
  for (int mt = 0; mt < 2; ++mt) {
    const floatx4 acc = mt ? acc1 : acc0;
#pragma unroll
    for (int r = 0; r < 4; ++r) {
      const int qq = (qt << 5) + (mt << 4) + (kg << 2) + r;
      if (qq < 253) out_b[qq * 128] = f2bf(fmaxf(acc[r] + bv, 0.f));
    }
  }
}

// ---------------------------------------------------------------------------
// k_rest: one block per batch. LDS layout [row][128] bf16 with byte ^=
// ((row>>1)&7)<<4 (rows accessed at step 2 -> 8 slots -> 2-way = free).
// Wave w: m-tile mt = w & (NMT-1), covers NMT ot's (og = w/NMT). No wave
// reads duplicate A-fragments. Valid-row math guarantees valid outputs only
// read valid inputs; garbage rows feed only masked (qq>=Mout) lanes.
// ---------------------------------------------------------------------------
__device__ __forceinline__ int swz(int row) { return ((row >> 1) & 7) << 4; }

template<int NMT>
__device__ __forceinline__ void conv_layer(const char* bi, char* bo,
                                           const unsigned short* __restrict__ WB,
                                           const float* __restrict__ bias,
                                           int Mout, int wid, int lane) {
  const int kg = lane >> 4, qb = lane & 15;
  const int mt = wid & (NMT - 1);
  const int og = wid / NMT;             // ot = og*NMT + j
  floatx4 acc[NMT];
#pragma unroll
  for (int i = 0; i < NMT; ++i) acc[i] = floatx4{0.f, 0.f, 0.f, 0.f};
#pragma unroll
  for (int tap = 0; tap < 5; ++tap)
#pragma unroll
    for (int cs = 0; cs < 4; ++cs) {
      const int ks = (tap << 2) + cs;
      const int row = 2 * ((mt << 4) + qb) + tap;
      const int byte = ((row << 8) + (cs << 6) + (kg << 4)) ^ swz(row);
      const bfrag8 a = *(const bfrag8*)(bi + byte);
#pragma unroll
      for (int j = 0; j < NMT; ++j) {
        const int ot = og * NMT + j;
        const bfrag8 bf = *(const bfrag8*)(WB + (((ot * 20 + ks) << 6) + lane) * 8);
        acc[j] = __builtin_amdgcn_mfma_f32_16x16x32_bf16(a, bf, acc[j], 0, 0, 0);
      }
    }
#pragma unroll
  for (int j = 0; j < NMT; ++j) {
    const int ot = og * NMT + j;
    const int o = (ot << 4) + qb;
    const float bv = bias[o];
#pragma unroll
    for (int r = 0; r < 4; ++r) {
      const int qq = (mt << 4) + (kg << 2) + r;
      if (qq < Mout) {
        const float v = fmaxf(acc[j][r] + bv, 0.f);
        const int byte = ((qq << 8) + (o << 1)) ^ swz(qq);
        *(unsigned short*)(bo + byte) = f2bf(v);
      }
    }
  }
}

__global__ __launch_bounds__(512)
void k_rest(const unsigned short* __restrict__ A0, const unsigned short* __restrict__ WBr,
            const float* __restrict__ br, const float* __restrict__ de,
            const float* __restrict__ w1, const float* __restrict__ b1,
            const float* __restrict__ w2, const float* __restrict__ b2,
            const float* __restrict__ w3, const float* __restrict__ b3,
            float* __restrict__ out) {
  __shared__ char bufIn[260 * 256];     // 66.6 KB  (layer1 input, rows 0..252 valid)
  __shared__ char bufA[136 * 256];      // 34.8 KB
  __shared__ char bufB[68 * 256];       // 17.4 KB
  __shared__ float h1[64], h2[32];
  const int tid = threadIdx.x;
  const int lane = tid & 63, wid = tid >> 6;
  const int b = blockIdx.x;

  // ---- stage A0 (253 rows x 256B) into swizzled LDS, wide parallel loads --
  const char* a0b = (const char*)(A0 + (size_t)b * 260 * 128);
  for (int idx = tid; idx < 253 * 16; idx += 512) {
    const int row = idx >> 4, seg = idx & 15;
    const float4v v = *(const float4v*)(a0b + (row << 8) + (seg << 4));
    *(float4v*)(bufIn + (((row << 8) + (seg << 4)) ^ swz(row))) = v;
  }
  __syncthreads();

  conv_layer<8>(bufIn, bufA, WBr + 0 * 81920, br + 0,   125, wid, lane);
  __syncthreads();
  conv_layer<4>(bufA, bufB, WBr + 1 * 81920, br + 128,  61, wid, lane);
  __syncthreads();
  conv_layer<2>(bufB, bufA, WBr + 2 * 81920, br + 256,  29, wid, lane);
  __syncthreads();
  conv_layer<1>(bufA, bufB, WBr + 3 * 81920, br + 384,  13, wid, lane);
  __syncthreads();
  conv_layer<1>(bufB, bufA, WBr + 4 * 81920, br + 512,   5, wid, lane);
  __syncthreads();
  conv_layer<1>(bufA, bufB, WBr + 5 * 81920, br + 640,   1, wid, lane);
  __syncthreads();

  // ---- head. bufB row 0 (swz identity) holds the 128 bf16 features. ------
  const unsigned short* o6 = (const unsigned short*)bufB;
  {                                     // h1: 64 outs x 8 threads each
    const int o1 = tid >> 3, part = tid & 7;
    const int j0 = part * 18;
    const int j1 = (j0 + 18 < 139) ? j0 + 18 : 139;
    float s = 0.f;
    const float* wrow = w1 + o1 * 139;
    for (int j = j0; j < j1; ++j) {
      const float x = (j < 128) ? bf2f(o6[j]) : de[b * 11 + (j - 128)];
      s += wrow[j] * x;
    }
    s += __shfl_down(s, 4, 64);
    s += __shfl_down(s, 2, 64);
    s += __shfl_down(s, 1, 64);
    if (part == 0) h1[o1] = fmaxf(s + b1[o1], 0.f);
  }
  __syncthreads();
  if (tid < 64) {                       // h2: 32 outs x 2 threads each
    const int o2 = tid >> 1, part = tid & 1;
    float s = 0.f;
    const float* wrow = w2 + o2 * 64 + part * 32;
    for (int j = 0; j < 32; ++j) s += wrow[j] * h1[part * 32 + j];
    s += __shfl_down(s, 1, 64);
    if (part == 0) h2[o2] = fmaxf(s + b2[o2], 0.f);
  }
  __syncthreads();
  if (tid < 32) {
    float s = w3[tid] * h2[tid];
    s += __shfl_down(s, 16, 64);
    s += __shfl_down(s, 8, 64);
    s += __shfl_down(s, 4, 64);
    s += __shfl_down(s, 2, 64);
    s += __shfl_down(s, 1, 64);
    if (tid == 0) out[b] = s + b3[0];
  }
}

// ---------------------------------------------------------------------------
extern "C" void kernel_launch(void* const* d_in, const int* in_sizes, int n_in,
                              void* d_out, int out_size, void* d_ws, size_t ws_size,
                              hipStream_t stream) {
  const int*   tokens = (const int*)  d_in[0];
  const float* de     = (const float*)d_in[1];
  const float* emb    = (const float*)d_in[2];
  const float* v0     = (const float*)d_in[3];
  const float* g0     = (const float*)d_in[4];
  const float* b0     = (const float*)d_in[5];
  const float* vr     = (const float*)d_in[6];
  const float* gr     = (const float*)d_in[7];
  const float* br     = (const float*)d_in[8];
  const float* w1     = (const float*)d_in[9];
  const float* b1     = (const float*)d_in[10];
  const float* w2     = (const float*)d_in[11];
  const float* b2     = (const float*)d_in[12];
  const float* w3     = (const float*)d_in[13];
  const float* b3     = (const float*)d_in[14];
  float* out = (float*)d_out;

  char* w = (char*)d_ws;
  unsigned short* WB0 = (unsigned short*)(w + 0);         // 128x1600 bf16
  unsigned short* WBr = (unsigned short*)(w + 409600);    // 6 x 128x640 bf16
  unsigned short* In0 = (unsigned short*)(w + 1392640);   // [64][516][320] bf16
  unsigned short* A0  = (unsigned short*)(w + 22528000);  // [64][260][128] bf16

  hipLaunchKernelGGL(k_prep, dim3(896 + 2048), dim3(256), 0, stream,
                     v0, g0, vr, gr, tokens, emb, WB0, WBr, In0);
  hipLaunchKernelGGL(k_conv0, dim3(8, 64), dim3(512), 0, stream, In0, A0, WB0, b0);
  hipLaunchKernelGGL(k_rest, dim3(64), dim3(512), 0, stream,
                     A0, WBr, br, de, w1, b1, w2, b2, w3, b3, out);
}

// Round 4
// 84.712 us; speedup vs baseline: 3.6260x; 1.3169x over previous
//
#include <hip/hip_runtime.h>

// ---------------------------------------------------------------------------
// Devault_Single_CCNN: only the LAST timestep feeds the head -> compute only
// the causal receptive field. Every layer is a stride-2 kernel-5 conv in
// index space: Out[q] = sum_k W[k] In[2q+k], lengths 509->253->...->1.
// bf16 MFMA 16x16x32, fp32 accumulate. 4 dispatches:
//   k_prep : weight-norm + MFMA-B pre-swizzle (WB0, WBr)
//   k_conv0: layer 0, K split by taps across 2 block sets (kc=0: taps 0-1,
//            kc=1: taps 2-4). Block = 64 q x 128 o, 4 waves, NMT=4 NOT=2.
//            Embedding rows are gathered fp32->bf16 directly into LDS.
//            Writes fp32 partials P0/P1 (pre-bias).
//   k_rest : layers 1-6 + FC head; staging fuses P0+P1+b0+relu -> LDS.
// ---------------------------------------------------------------------------

typedef __attribute__((ext_vector_type(8))) short bfrag8;   // 8 bf16
typedef __attribute__((ext_vector_type(4))) float floatx4;  // MFMA acc
typedef __attribute__((ext_vector_type(4))) short short4v;
typedef __attribute__((ext_vector_type(4))) float float4v;

__device__ __forceinline__ unsigned short f2bf(float f) {
  union { float f; unsigned u; } v; v.f = f;
  unsigned r = v.u + 0x7fffu + ((v.u >> 16) & 1u);  // RNE
  return (unsigned short)(r >> 16);
}
__device__ __forceinline__ float bf2f(unsigned short h) {
  union { unsigned u; float f; } v; v.u = ((unsigned)h) << 16;
  return v.f;
}

// ---------------------------------------------------------------------------
// k_prep: weight-norm + MFMA-B pre-swizzle.
// WB layout: WB[((ot*NKS + ks)*64 + lane)*8 + i], lane=(o&15)|(kg<<4),
//            kk = ks*32 + kg*8 + i, kk = tap*CPAD + c  (CPAD0=320, c>=300 -> 0).
// ---------------------------------------------------------------------------
__global__ __launch_bounds__(256)
void k_prep(const float* __restrict__ v0, const float* __restrict__ g0,
            const float* __restrict__ vr, const float* __restrict__ gr,
            unsigned short* __restrict__ WB0, unsigned short* __restrict__ WBr) {
  __shared__ float red[4];
  const int tid = threadIdx.x;
  const int blk = blockIdx.x;
  if (blk < 128) {                       // layer 0: K=1500 -> pad 1600
    const int o = blk;
    const float* v = v0 + o * 1500;
    float ss = 0.f;
    for (int i = tid; i < 1500; i += 256) { float x = v[i]; ss += x * x; }
    for (int off = 32; off; off >>= 1) ss += __shfl_down(ss, off, 64);
    if ((tid & 63) == 0) red[tid >> 6] = ss;
    __syncthreads();
    const float scale = g0[o] * rsqrtf(red[0] + red[1] + red[2] + red[3]);
    const int ot = o >> 4;
    for (int kk = tid; kk < 1600; kk += 256) {
      const int tap = kk / 320, c = kk % 320;
      const float w = (c < 300) ? v[c * 5 + tap] * scale : 0.f;
      const int ks = kk >> 5;
      const int lane = (o & 15) | (((kk >> 3) & 3) << 4);
      WB0[(((ot * 50 + ks) * 64 + lane) << 3) | (kk & 7)] = f2bf(w);
    }
  } else {                               // layers 1..6: K=640
    const int idx = blk - 128;
    const int l = idx >> 7, o = idx & 127;
    const float* v = vr + (size_t)(l * 128 + o) * 640;
    float ss = 0.f;
    for (int i = tid; i < 640; i += 256) { float x = v[i]; ss += x * x; }
    for (int off = 32; off; off >>= 1) ss += __shfl_down(ss, off, 64);
    if ((tid & 63) == 0) red[tid >> 6] = ss;
    __syncthreads();
    const float scale = gr[l * 128 + o] * rsqrtf(red[0] + red[1] + red[2] + red[3]);
    unsigned short* WB = WBr + (size_t)l * 81920;
    const int ot = o >> 4;
    for (int kk = tid; kk < 640; kk += 256) {
      const int tap = kk >> 7, c = kk & 127;
      const float w = v[c * 5 + tap] * scale;
      const int ks = kk >> 5;
      const int lane = (o & 15) | (((kk >> 3) & 3) << 4);
      WB[(((ot * 20 + ks) * 64 + lane) << 3) | (kk & 7)] = f2bf(w);
    }
  }
}

// ---------------------------------------------------------------------------
// k_conv0: layer 0 with tap-split K. Grid (8, 64): x = qt(0..3) | kc<<2.
// Block: 64 q-rows x 128 o, 256 threads (4 waves). Wave og: NOT=2 ot's
// {2og, 2og+1}, NMT=4 m-tiles (all 64 q). A staged in LDS (pitch 608 B =
// 304 ch, c>=300 zero; zero-weight columns absorb the 2-chunk overread).
// kc=0 -> taps {0,1}, rows [2q0, 2q0+127]; kc=1 -> taps {2,3,4},
// rows [2q0+2, 2q0+130]. fp32 partials, no bias/relu here.
// ---------------------------------------------------------------------------
__global__ __launch_bounds__(256, 2)
void k_conv0(const int* __restrict__ tokens, const float* __restrict__ emb,
             const unsigned short* __restrict__ WB,
             float* __restrict__ P0, float* __restrict__ P1) {
  __shared__ char buf[130 * 608];        // 79.0 KB (row 129 = spill pad)
  __shared__ int toks[130];
  const int tid = threadIdx.x;
  const int qt = blockIdx.x & 3, kc = blockIdx.x >> 2;
  const int b = blockIdx.y;
  const int q0 = qt << 6;
  const int row_lo = (q0 << 1) + (kc << 1);
  const int nrows = 128 + kc;            // 128 (kc=0) / 129 (kc=1)
  if (tid < 130) {
    const int p = row_lo + tid;
    toks[tid] = (tid < nrows && p < 509) ? tokens[(b << 11) + 1539 + p] : -1;
  }
  __syncthreads();
  // ---- gather emb rows -> bf16 LDS (invalid rows / pad chunk -> zeros) ----
#pragma unroll 8
  for (int i = 0; i < 40; ++i) {
    const int idx = tid + (i << 8);
    if (idx < 130 * 76) {
      const int r = idx / 76, s = idx - r * 76;
      short4v o = {0, 0, 0, 0};
      const int tok = toks[r];
      if (tok >= 0 && s < 75) {
        const float4v v = *(const float4v*)(emb + (size_t)tok * 300 + (s << 2));
        o[0] = (short)f2bf(v[0]); o[1] = (short)f2bf(v[1]);
        o[2] = (short)f2bf(v[2]); o[3] = (short)f2bf(v[3]);
      }
      *(short4v*)(buf + r * 608 + (s << 3)) = o;
    }
  }
  __syncthreads();
  // ---- main MFMA loop ----
  const int lane = tid & 63;
  const int og = tid >> 6;               // 0..3
  const int qb = lane & 15, kg = lane >> 4;
  floatx4 acc[4][2];
#pragma unroll
  for (int m = 0; m < 4; ++m) {
    acc[m][0] = floatx4{0.f, 0.f, 0.f, 0.f};
    acc[m][1] = floatx4{0.f, 0.f, 0.f, 0.f};
  }
  const unsigned short* wb0 = WB + (size_t)(((og * 100) << 6) + lane) * 8;
  const int tcnt = kc ? 3 : 2;
  const int ksbase = kc ? 20 : 0;
  for (int tl = 0; tl < tcnt; ++tl) {    // tap-local
    const int rb = tl + (qb << 1);
#pragma unroll
    for (int cs = 0; cs < 10; ++cs) {
      const int ks = ksbase + tl * 10 + cs;
      const unsigned short* wb = wb0 + (ks << 9);
      const bfrag8 bf0 = *(const bfrag8*)(wb);
      const bfrag8 bf1 = *(const bfrag8*)(wb + (50 << 9));  // ot+1
      const int cb = (cs << 6) + (kg << 4);
#pragma unroll
      for (int m = 0; m < 4; ++m) {
        const bfrag8 a = *(const bfrag8*)(buf + (rb + (m << 5)) * 608 + cb);
        acc[m][0] = __builtin_amdgcn_mfma_f32_16x16x32_bf16(a, bf0, acc[m][0], 0, 0, 0);
        acc[m][1] = __builtin_amdgcn_mfma_f32_16x16x32_bf16(a, bf1, acc[m][1], 0, 0, 0);
      }
    }
  }
  // ---- store fp32 partials; P rows padded to 256, rows>=253 unread ----
  float* pb = (kc ? P1 : P0) + ((size_t)b << 15);
#pragma unroll
  for (int m = 0; m < 4; ++m)
#pragma unroll
    for (int j = 0; j < 2; ++j) {
      const int o = (((og << 1) + j) << 4) + qb;
#pragma unroll
      for (int r = 0; r < 4; ++r) {
        const int q = q0 + (m << 4) + (kg << 2) + r;
        pb[(q << 7) + o] = acc[m][j][r];
      }
    }
}

// ---------------------------------------------------------------------------
// k_rest: one block per batch. LDS tiles [row][128] bf16, byte ^=
// ((row>>1)&7)<<4 swizzle. Wave w: mt = w&(NMT-1), og = w/NMT.
// ---------------------------------------------------------------------------
__device__ __forceinline__ int swz(int row) { return ((row >> 1) & 7) << 4; }

template<int NMT>
__device__ __forceinline__ void conv_layer(const char* bi, char* bo,
                                           const unsigned short* __restrict__ WB,
                                           const float* __restrict__ bias,
                                           int Mout, int wid, int lane) {
  const int kg = lane >> 4, qb = lane & 15;
  const int mt = wid & (NMT - 1);
  const int og = wid / NMT;
  floatx4 acc[NMT];
#pragma unroll
  for (int i = 0; i < NMT; ++i) acc[i] = floatx4{0.f, 0.f, 0.f, 0.f};
#pragma unroll
  for (int tap = 0; tap < 5; ++tap)
#pragma unroll
    for (int cs = 0; cs < 4; ++cs) {
      const int ks = (tap << 2) + cs;
      const int row = 2 * ((mt << 4) + qb) + tap;
      const int byte = ((row << 8) + (cs << 6) + (kg << 4)) ^ swz(row);
      const bfrag8 a = *(const bfrag8*)(bi + byte);
#pragma unroll
      for (int j = 0; j < NMT; ++j) {
        const int ot = og * NMT + j;
        const bfrag8 bf = *(const bfrag8*)(WB + (((ot * 20 + ks) << 6) + lane) * 8);
        acc[j] = __builtin_amdgcn_mfma_f32_16x16x32_bf16(a, bf, acc[j], 0, 0, 0);
      }
    }
#pragma unroll
  for (int j = 0; j < NMT; ++j) {
    const int ot = og * NMT + j;
    const int o = (ot << 4) + qb;
    const float bv = bias[o];
#pragma unroll
    for (int r = 0; r < 4; ++r) {
      const int qq = (mt << 4) + (kg << 2) + r;
      if (qq < Mout) {
        const float v = fmaxf(acc[j][r] + bv, 0.f);
        const int byte = ((qq << 8) + (o << 1)) ^ swz(qq);
        *(unsigned short*)(bo + byte) = f2bf(v);
      }
    }
  }
}

__global__ __launch_bounds__(512)
void k_rest(const float* __restrict__ P0, const float* __restrict__ P1,
            const float* __restrict__ b0, const unsigned short* __restrict__ WBr,
            const float* __restrict__ br, const float* __restrict__ de,
            const float* __restrict__ w1, const float* __restrict__ b1,
            const float* __restrict__ w2, const float* __restrict__ b2,
            const float* __restrict__ w3, const float* __restrict__ b3,
            float* __restrict__ out) {
  __shared__ char bufIn[260 * 256];     // 66.6 KB (layer-1 input)
  __shared__ char bufA[136 * 256];      // 34.8 KB
  __shared__ char bufB[68 * 256];      // 17.4 KB
  __shared__ float h1[64], h2[32];
  const int tid = threadIdx.x;
  const int lane = tid & 63, wid = tid >> 6;
  const int b = blockIdx.x;

  // ---- stage: A0 = relu(P0 + P1 + b0), fp32 -> bf16, swizzled LDS ----
  const float* p0b = P0 + ((size_t)b << 15);
  const float* p1b = P1 + ((size_t)b << 15);
  for (int idx = tid; idx < 253 * 32; idx += 512) {
    const int row = idx >> 5, seg = idx & 31;
    const float4v x = *(const float4v*)(p0b + (row << 7) + (seg << 2));
    const float4v y = *(const float4v*)(p1b + (row << 7) + (seg << 2));
    const float4v bb = *(const float4v*)(b0 + (seg << 2));
    short4v o;
    o[0] = (short)f2bf(fmaxf(x[0] + y[0] + bb[0], 0.f));
    o[1] = (short)f2bf(fmaxf(x[1] + y[1] + bb[1], 0.f));
    o[2] = (short)f2bf(fmaxf(x[2] + y[2] + bb[2], 0.f));
    o[3] = (short)f2bf(fmaxf(x[3] + y[3] + bb[3], 0.f));
    *(short4v*)(bufIn + (((row << 8) + (seg << 3)) ^ swz(row))) = o;
  }
  __syncthreads();

  conv_layer<8>(bufIn, bufA, WBr + 0 * 81920, br + 0,   125, wid, lane);
  __syncthreads();
  conv_layer<4>(bufA, bufB, WBr + 1 * 81920, br + 128,  61, wid, lane);
  __syncthreads();
  conv_layer<2>(bufB, bufA, WBr + 2 * 81920, br + 256,  29, wid, lane);
  __syncthreads();
  conv_layer<1>(bufA, bufB, WBr + 3 * 81920, br + 384,  13, wid, lane);
  __syncthreads();
  conv_layer<1>(bufB, bufA, WBr + 4 * 81920, br + 512,   5, wid, lane);
  __syncthreads();
  conv_layer<1>(bufA, bufB, WBr + 5 * 81920, br + 640,   1, wid, lane);
  __syncthreads();

  // ---- head: combo = [bufB row 0 (swz identity), de] -> 64 -> 32 -> 1 ----
  const unsigned short* o6 = (const unsigned short*)bufB;
  {                                     // h1: 64 outs x 8 threads
    const int o1 = tid >> 3, part = tid & 7;
    const int j0 = part * 18;
    const int j1 = (j0 + 18 < 139) ? j0 + 18 : 139;
    float s = 0.f;
    const float* wrow = w1 + o1 * 139;
    for (int j = j0; j < j1; ++j) {
      const float x = (j < 128) ? bf2f(o6[j]) : de[b * 11 + (j - 128)];
      s += wrow[j] * x;
    }
    s += __shfl_down(s, 4, 64);
    s += __shfl_down(s, 2, 64);
    s += __shfl_down(s, 1, 64);
    if (part == 0) h1[o1] = fmaxf(s + b1[o1], 0.f);
  }
  __syncthreads();
  if (tid < 64) {                       // h2: 32 outs x 2 threads
    const int o2 = tid >> 1, part = tid & 1;
    float s = 0.f;
    const float* wrow = w2 + o2 * 64 + part * 32;
    for (int j = 0; j < 32; ++j) s += wrow[j] * h1[part * 32 + j];
    s += __shfl_down(s, 1, 64);
    if (part == 0) h2[o2] = fmaxf(s + b2[o2], 0.f);
  }
  __syncthreads();
  if (tid < 32) {
    float s = w3[tid] * h2[tid];
    s += __shfl_down(s, 16, 64);
    s += __shfl_down(s, 8, 64);
    s += __shfl_down(s, 4, 64);
    s += __shfl_down(s, 2, 64);
    s += __shfl_down(s, 1, 64);
    if (tid == 0) out[b] = s + b3[0];
  }
}

// ---------------------------------------------------------------------------
extern "C" void kernel_launch(void* const* d_in, const int* in_sizes, int n_in,
                              void* d_out, int out_size, void* d_ws, size_t ws_size,
                              hipStream_t stream) {
  const int*   tokens = (const int*)  d_in[0];
  const float* de     = (const float*)d_in[1];
  const float* emb    = (const float*)d_in[2];
  const float* v0     = (const float*)d_in[3];
  const float* g0     = (const float*)d_in[4];
  const float* b0     = (const float*)d_in[5];
  const float* vr     = (const float*)d_in[6];
  const float* gr     = (const float*)d_in[7];
  const float* br     = (const float*)d_in[8];
  const float* w1     = (const float*)d_in[9];
  const float* b1     = (const float*)d_in[10];
  const float* w2     = (const float*)d_in[11];
  const float* b2     = (const float*)d_in[12];
  const float* w3     = (const float*)d_in[13];
  const float* b3     = (const float*)d_in[14];
  float* out = (float*)d_out;

  char* w = (char*)d_ws;
  unsigned short* WB0 = (unsigned short*)(w + 0);         // 128x1600 bf16
  unsigned short* WBr = (unsigned short*)(w + 409600);    // 6 x 128x640 bf16
  float* P0 = (float*)(w + 1392640);                      // [64][256][128] fp32
  float* P1 = (float*)(w + 1392640 + 8388608);            // [64][256][128] fp32

  hipLaunchKernelGGL(k_prep, dim3(896), dim3(256), 0, stream, v0, g0, vr, gr, WB0, WBr);
  hipLaunchKernelGGL(k_conv0, dim3(8, 64), dim3(256), 0, stream, tokens, emb, WB0, P0, P1);
  hipLaunchKernelGGL(k_rest, dim3(64), dim3(512), 0, stream,
                     P0, P1, b0, WBr, br, de, w1, b1, w2, b2, w3, b3, out);
}

// Round 5
// 68.490 us; speedup vs baseline: 4.4848x; 1.2368x over previous
//
#include <hip/hip_runtime.h>

// ---------------------------------------------------------------------------
// Devault_Single_CCNN: only the LAST timestep feeds the head -> compute only
// the causal receptive field. Every layer is a stride-2 kernel-5 conv in
// index space: Out[q] = sum_k W[k] In[2q+k], lengths 509->253->...->1.
// bf16 MFMA 16x16x32, fp32 accumulate. 3 dispatches:
//   k_prep : weight-norm + MFMA-B pre-swizzle (WB0, WBr)
//   k_conv0: layer 0 full-K (grid 4x64, 256thr, VGPR-rich), emb gathered
//            straight into LDS (pitch 616B = 2-way-free for step-2 rows),
//            B register-preloaded per tap; writes final bf16 A0 (+bias,relu)
//   k_rest : layers 1-6 + FC head, one block/batch, 512 thr. Register-tiled
//            convs: B quarter-preloaded into VGPR arrays (static idx), A from
//            swizzled LDS. All-LDS activation ping-pong.
// ---------------------------------------------------------------------------

typedef __attribute__((ext_vector_type(8))) short bfrag8;   // 8 bf16
typedef __attribute__((ext_vector_type(4))) float floatx4;  // MFMA acc
typedef __attribute__((ext_vector_type(4))) short short4v;
typedef __attribute__((ext_vector_type(4))) float float4v;

__device__ __forceinline__ unsigned short f2bf(float f) {
  union { float f; unsigned u; } v; v.f = f;
  unsigned r = v.u + 0x7fffu + ((v.u >> 16) & 1u);  // RNE
  return (unsigned short)(r >> 16);
}
__device__ __forceinline__ float bf2f(unsigned short h) {
  union { unsigned u; float f; } v; v.u = ((unsigned)h) << 16;
  return v.f;
}
__device__ __forceinline__ int swz(int row) { return ((row >> 1) & 7) << 4; }

// ---------------------------------------------------------------------------
// k_prep: weight-norm + MFMA-B pre-swizzle.
// WB layout: WB[((ot*NKS + ks)*64 + lane)*8 + i], lane=(o&15)|(kg<<4),
//            kk = ks*32 + kg*8 + i, kk = tap*CPAD + c (CPAD0=320, c>=300 -> 0)
// ---------------------------------------------------------------------------
__global__ __launch_bounds__(256)
void k_prep(const float* __restrict__ v0, const float* __restrict__ g0,
            const float* __restrict__ vr, const float* __restrict__ gr,
            unsigned short* __restrict__ WB0, unsigned short* __restrict__ WBr) {
  __shared__ float red[4];
  const int tid = threadIdx.x;
  const int blk = blockIdx.x;
  if (blk < 128) {                       // layer 0: K=1500 -> pad 1600
    const int o = blk;
    const float* v = v0 + o * 1500;
    float ss = 0.f;
    for (int i = tid; i < 1500; i += 256) { float x = v[i]; ss += x * x; }
    for (int off = 32; off; off >>= 1) ss += __shfl_down(ss, off, 64);
    if ((tid & 63) == 0) red[tid >> 6] = ss;
    __syncthreads();
    const float scale = g0[o] * rsqrtf(red[0] + red[1] + red[2] + red[3]);
    const int ot = o >> 4;
    for (int kk = tid; kk < 1600; kk += 256) {
      const int tap = kk / 320, c = kk % 320;
      const float w = (c < 300) ? v[c * 5 + tap] * scale : 0.f;
      const int ks = kk >> 5;
      const int lane = (o & 15) | (((kk >> 3) & 3) << 4);
      WB0[(((ot * 50 + ks) * 64 + lane) << 3) | (kk & 7)] = f2bf(w);
    }
  } else {                               // layers 1..6: K=640
    const int idx = blk - 128;
    const int l = idx >> 7, o = idx & 127;
    const float* v = vr + (size_t)(l * 128 + o) * 640;
    float ss = 0.f;
    for (int i = tid; i < 640; i += 256) { float x = v[i]; ss += x * x; }
    for (int off = 32; off; off >>= 1) ss += __shfl_down(ss, off, 64);
    if ((tid & 63) == 0) red[tid >> 6] = ss;
    __syncthreads();
    const float scale = gr[l * 128 + o] * rsqrtf(red[0] + red[1] + red[2] + red[3]);
    unsigned short* WB = WBr + (size_t)l * 81920;
    const int ot = o >> 4;
    for (int kk = tid; kk < 640; kk += 256) {
      const int tap = kk >> 7, c = kk & 127;
      const float w = v[c * 5 + tap] * scale;
      const int ks = kk >> 5;
      const int lane = (o & 15) | (((kk >> 3) & 3) << 4);
      WB[(((ot * 20 + ks) * 64 + lane) << 3) | (kk & 7)] = f2bf(w);
    }
  }
}

// ---------------------------------------------------------------------------
// k_conv0: layer 0, full K. Grid (4 qt, 64 b) x 256 thr (4 waves).
// LDS pitch 616B: step-2-row ds_read_b128 start-banks stride 20 dwords -> 8
// distinct 4-bank groups x2 = 2-way (free). Channels 300-319 zero-padded in
// WB0, so the 24B tail overread of each row hits zero weights (harmless).
// Wave og: ot {2og,2og+1}, all 4 m-tiles. B preloaded 20 frags per tap.
// ---------------------------------------------------------------------------
__global__ __launch_bounds__(256, 1)
void k_conv0(const int* __restrict__ tokens, const float* __restrict__ emb,
             const unsigned short* __restrict__ WB, const float* __restrict__ b0,
             unsigned short* __restrict__ A0) {
  __shared__ char buf[131 * 616 + 64];
  __shared__ int toks[131];
  const int tid = threadIdx.x;
  const int qt = blockIdx.x, b = blockIdx.y;
  const int q0 = qt << 6;
  const int row_lo = q0 << 1;
  if (tid < 131) {
    const int p = row_lo + tid;
    toks[tid] = (p < 509) ? tokens[(b << 11) + 1539 + p] : -1;
  }
  __syncthreads();
  // stage emb rows -> bf16 LDS (77 8B-chunks/row; s>=75 or bad row -> 0)
  for (int idx = tid; idx < 131 * 77; idx += 256) {
    const int r = idx / 77, s = idx - r * 77;
    short4v o = {0, 0, 0, 0};
    const int tok = toks[r];
    if (tok >= 0 && s < 75) {
      const float4v v = *(const float4v*)(emb + (size_t)tok * 300 + (s << 2));
      o[0] = (short)f2bf(v[0]); o[1] = (short)f2bf(v[1]);
      o[2] = (short)f2bf(v[2]); o[3] = (short)f2bf(v[3]);
    }
    *(short4v*)(buf + r * 616 + (s << 3)) = o;
  }
  __syncthreads();
  const int lane = tid & 63, og = tid >> 6;
  const int qb = lane & 15, kg = lane >> 4;
  floatx4 acc[4][2];
#pragma unroll
  for (int m = 0; m < 4; ++m) {
    acc[m][0] = floatx4{0.f, 0.f, 0.f, 0.f};
    acc[m][1] = floatx4{0.f, 0.f, 0.f, 0.f};
  }
  const unsigned short* wb0 = WB + (size_t)((((og << 1) * 50) << 6) + lane) * 8;
#pragma unroll
  for (int tap = 0; tap < 5; ++tap) {
    bfrag8 bf0[10], bf1[10];
#pragma unroll
    for (int cs = 0; cs < 10; ++cs) {
      const int ks = tap * 10 + cs;
      bf0[cs] = *(const bfrag8*)(wb0 + (ks << 9));
      bf1[cs] = *(const bfrag8*)(wb0 + ((ks + 50) << 9));
    }
#pragma unroll
    for (int cs = 0; cs < 10; ++cs) {
      const int cb = (cs << 6) + (kg << 4);
#pragma unroll
      for (int m = 0; m < 4; ++m) {
        const int row = (((m << 4) + qb) << 1) + tap;
        const bfrag8 a = *(const bfrag8*)(buf + row * 616 + cb);
        acc[m][0] = __builtin_amdgcn_mfma_f32_16x16x32_bf16(a, bf0[cs], acc[m][0], 0, 0, 0);
        acc[m][1] = __builtin_amdgcn_mfma_f32_16x16x32_bf16(a, bf1[cs], acc[m][1], 0, 0, 0);
      }
    }
  }
  // store bf16 with bias+relu; rows q0..q0+63 (<260 pad); garbage rows >=253
  // are never read downstream.
  unsigned short* out_b = A0 + ((size_t)b * 260 + q0) * 128;
  const int o0 = (og << 5) + qb;
  const float bv0 = b0[o0], bv1 = b0[o0 + 16];
#pragma unroll
  for (int m = 0; m < 4; ++m)
#pragma unroll
    for (int r = 0; r < 4; ++r) {
      const int ql = (m << 4) + (kg << 2) + r;
      out_b[ql * 128 + o0]      = f2bf(fmaxf(acc[m][0][r] + bv0, 0.f));
      out_b[ql * 128 + o0 + 16] = f2bf(fmaxf(acc[m][1][r] + bv1, 0.f));
    }
}

// ---------------------------------------------------------------------------
// k_rest conv building block. Wave tile = NMTW m-tiles x NOTW ot's; B
// quarter-preloaded (NOTW*5 frags, static indices -> VGPRs), A from swizzled
// 256B-pitch LDS. All stores in-bounds; garbage rows feed only masked paths.
// ---------------------------------------------------------------------------
template<int NMTW, int NOTW, int MTILES>
__device__ __forceinline__ void conv_rest(const char* bi, char* bo,
    const unsigned short* __restrict__ WBl, const float* __restrict__ bias,
    int w, int qb, int kg, int lane) {
  constexpr int NG = MTILES / NMTW;
  const int mg = (NG == 1) ? 0 : (w % NG);
  const int og = (NG == 1) ? w : (w / NG);
  if (og >= 8 / NOTW) return;
  floatx4 acc[NMTW][NOTW];
#pragma unroll
  for (int m = 0; m < NMTW; ++m)
#pragma unroll
    for (int j = 0; j < NOTW; ++j) acc[m][j] = floatx4{0.f, 0.f, 0.f, 0.f};
#pragma unroll
  for (int quarter = 0; quarter < 4; ++quarter) {
    bfrag8 bfs[NOTW][5];
#pragma unroll
    for (int j = 0; j < NOTW; ++j)
#pragma unroll
      for (int t = 0; t < 5; ++t)
        bfs[j][t] = *(const bfrag8*)(WBl +
            (size_t)(((((og * NOTW + j) * 20) + quarter * 5 + t) << 6) + lane) * 8);
#pragma unroll
    for (int t = 0; t < 5; ++t) {
      const int ks = quarter * 5 + t, tap = ks >> 2, cs = ks & 3;
#pragma unroll
      for (int m = 0; m < NMTW; ++m) {
        const int row = (((((mg * NMTW + m) << 4) + qb)) << 1) + tap;
        const int byte = ((row << 8) + (cs << 6) + (kg << 4)) ^ swz(row);
        const bfrag8 a = *(const bfrag8*)(bi + byte);
#pragma unroll
        for (int j = 0; j < NOTW; ++j)
          acc[m][j] = __builtin_amdgcn_mfma_f32_16x16x32_bf16(a, bfs[j][t], acc[m][j], 0, 0, 0);
      }
    }
  }
#pragma unroll
  for (int m = 0; m < NMTW; ++m)
#pragma unroll
    for (int j = 0; j < NOTW; ++j) {
      const int o = ((og * NOTW + j) << 4) + qb;
      const float bv = bias[o];
#pragma unroll
      for (int r = 0; r < 4; ++r) {
        const int qq = ((mg * NMTW + m) << 4) + (kg << 2) + r;
        const int byte2 = ((qq << 8) + (o << 1)) ^ swz(qq);
        *(unsigned short*)(bo + byte2) = f2bf(fmaxf(acc[m][j][r] + bv, 0.f));
      }
    }
}

// ---------------------------------------------------------------------------
// k_rest: one block per batch, 512 thr (8 waves). Layers 1-6 + head.
// LDS: bufIn 254 rows (L1 input), actP 128, actQ 68 (overread slack), h1/h2.
// Ping-pong: bufIn->P->Q->P->Q->P->Q; final feature = actQ row 0.
// ---------------------------------------------------------------------------
__global__ __launch_bounds__(512, 1)
void k_rest(const unsigned short* __restrict__ A0, const unsigned short* __restrict__ WBr,
            const float* __restrict__ br, const float* __restrict__ de,
            const float* __restrict__ w1, const float* __restrict__ b1,
            const float* __restrict__ w2, const float* __restrict__ b2,
            const float* __restrict__ w3, const float* __restrict__ b3,
            float* __restrict__ out) {
  __shared__ char lds[254 * 256 + 128 * 256 + 68 * 256 + 384 + 64];
  char* bufIn = lds;                    // 65,024 B
  char* actP  = lds + 65024;            // 32,768 B
  char* actQ  = lds + 97792;            // 17,408 B
  float* h1   = (float*)(lds + 115200); // 64 f
  float* h2   = (float*)(lds + 115456); // 32 f
  const int tid = threadIdx.x, b = blockIdx.x;
  const int lane = tid & 63, w = tid >> 6;
  const int qb = lane & 15, kg = lane >> 4;

  // ---- stage A0 (253 rows x 256B) into swizzled LDS ----
  const char* a0b = (const char*)(A0 + (size_t)b * 260 * 128);
  for (int idx = tid; idx < 253 * 16; idx += 512) {
    const int r = idx >> 4, s = idx & 15;
    *(float4v*)(bufIn + (((r << 8) + (s << 4)) ^ swz(r))) =
        *(const float4v*)(a0b + (r << 8) + (s << 4));
  }
  __syncthreads();

  conv_rest<2, 4, 8>(bufIn, actP, WBr,              br,       w, qb, kg, lane); // L1 M=125
  __syncthreads();
  conv_rest<2, 2, 4>(actP, actQ, WBr + 1 * 81920,   br + 128, w, qb, kg, lane); // L2 M=61
  __syncthreads();
  conv_rest<1, 2, 2>(actQ, actP, WBr + 2 * 81920,   br + 256, w, qb, kg, lane); // L3 M=29
  __syncthreads();
  conv_rest<1, 1, 1>(actP, actQ, WBr + 3 * 81920,   br + 384, w, qb, kg, lane); // L4 M=13
  __syncthreads();
  conv_rest<1, 1, 1>(actQ, actP, WBr + 4 * 81920,   br + 512, w, qb, kg, lane); // L5 M=5
  __syncthreads();
  conv_rest<1, 1, 1>(actP, actQ, WBr + 5 * 81920,   br + 640, w, qb, kg, lane); // L6 M=1
  __syncthreads();

  // ---- head: combo = [actQ row 0 (swz identity), de] -> 64 -> 32 -> 1 ----
  const unsigned short* o6 = (const unsigned short*)actQ;
  {                                     // h1: 64 outs x 8 threads
    const int o1 = tid >> 3, part = tid & 7;
    const int j0 = part * 18;
    const int j1 = (j0 + 18 < 139) ? j0 + 18 : 139;
    float s = 0.f;
    const float* wrow = w1 + o1 * 139;
    for (int j = j0; j < j1; ++j) {
      const float x = (j < 128) ? bf2f(o6[j]) : de[b * 11 + (j - 128)];
      s += wrow[j] * x;
    }
    s += __shfl_down(s, 4, 64);
    s += __shfl_down(s, 2, 64);
    s += __shfl_down(s, 1, 64);
    if (part == 0) h1[o1] = fmaxf(s + b1[o1], 0.f);
  }
  __syncthreads();
  if (tid < 64) {                       // h2: 32 outs x 2 threads
    const int o2 = tid >> 1, part = tid & 1;
    float s = 0.f;
    const float* wrow = w2 + o2 * 64 + part * 32;
    for (int j = 0; j < 32; ++j) s += wrow[j] * h1[part * 32 + j];
    s += __shfl_down(s, 1, 64);
    if (part == 0) h2[o2] = fmaxf(s + b2[o2], 0.f);
  }
  __syncthreads();
  if (tid < 32) {
    float s = w3[tid] * h2[tid];
    s += __shfl_down(s, 16, 64);
    s += __shfl_down(s, 8, 64);
    s += __shfl_down(s, 4, 64);
    s += __shfl_down(s, 2, 64);
    s += __shfl_down(s, 1, 64);
    if (tid == 0) out[b] = s + b3[0];
  }
}

// ---------------------------------------------------------------------------
extern "C" void kernel_launch(void* const* d_in, const int* in_sizes, int n_in,
                              void* d_out, int out_size, void* d_ws, size_t ws_size,
                              hipStream_t stream) {
  const int*   tokens = (const int*)  d_in[0];
  const float* de     = (const float*)d_in[1];
  const float* emb    = (const float*)d_in[2];
  const float* v0     = (const float*)d_in[3];
  const float* g0     = (const float*)d_in[4];
  const float* b0     = (const float*)d_in[5];
  const float* vr     = (const float*)d_in[6];
  const float* gr     = (const float*)d_in[7];
  const float* br     = (const float*)d_in[8];
  const float* w1     = (const float*)d_in[9];
  const float* b1     = (const float*)d_in[10];
  const float* w2     = (const float*)d_in[11];
  const float* b2     = (const float*)d_in[12];
  const float* w3     = (const float*)d_in[13];
  const float* b3     = (const float*)d_in[14];
  float* out = (float*)d_out;

  char* w = (char*)d_ws;
  unsigned short* WB0 = (unsigned short*)(w + 0);         // 128x1600 bf16
  unsigned short* WBr = (unsigned short*)(w + 409600);    // 6 x 128x640 bf16
  unsigned short* A0  = (unsigned short*)(w + 1392640);   // [64][260][128] bf16

  hipLaunchKernelGGL(k_prep, dim3(896), dim3(256), 0, stream, v0, g0, vr, gr, WB0, WBr);
  hipLaunchKernelGGL(k_conv0, dim3(4, 64), dim3(256), 0, stream, tokens, emb, WB0, b0, A0);
  hipLaunchKernelGGL(k_rest, dim3(64), dim3(512), 0, stream,
                     A0, WBr, br, de, w1, b1, w2, b2, w3, b3, out);
}